// Round 13
// baseline (497.084 us; speedup 1.0000x reference)
//
#include <hip/hip_runtime.h>

#define N_NODES 50000
#define N_EDGES 500000
#define EB 64
#define HST 136          // Hb row stride (u16): cols 0..127 data, 128..135 pad
#define W1K 176          // W1t row length (k padded 161->176, zeros beyond 160)
#define OUTC 320
#define NPIECE 25        // msg pieces: 0..3 m0 | 4..11 sg | 12..23 m1b | 24 ev(f32x3)
#define NBLK1 49
// fallback-kernel layout constants
#define KP1 200
#define KH  136
#define KV  104
#define WTS 40
#define INV_SQ3 0.57735026918962576f
#define INV_SQ2 0.70710678118654752f
#define INV_AVG 0.1f

typedef short bf16x8 __attribute__((ext_vector_type(8)));
typedef unsigned short u16;
typedef u16 u16x8 __attribute__((ext_vector_type(8)));
typedef float f32x16 __attribute__((ext_vector_type(16)));

__device__ __forceinline__ unsigned cvtpk(float lo, float hi) {
    unsigned r;
    asm("v_cvt_pk_bf16_f32 %0, %1, %2" : "=v"(r) : "v"(lo), "v"(hi));
    return r;
}
__device__ __forceinline__ u16 f2bf(float f) { return (u16)cvtpk(f, f); }
__device__ __forceinline__ float bf2f(u16 h) {
    union { unsigned u; float f; } x; x.u = ((unsigned)h) << 16; return x.f;
}
__device__ __forceinline__ float fsilu(float x) {
    return x * __builtin_amdgcn_rcpf(1.f + __expf(-x));
}

__device__ __forceinline__ void stage16(const float* g, u16* l, bool v) {
    float4 a0, a1, a2, a3;
    const float4 z = make_float4(0.f, 0.f, 0.f, 0.f);
    if (v) { a0 = *(const float4*)(g);     a1 = *(const float4*)(g + 4);
             a2 = *(const float4*)(g + 8); a3 = *(const float4*)(g + 12); }
    else   { a0 = z; a1 = z; a2 = z; a3 = z; }
    uint4 p0 = { cvtpk(a0.x, a0.y), cvtpk(a0.z, a0.w), cvtpk(a1.x, a1.y), cvtpk(a1.z, a1.w) };
    uint4 p1 = { cvtpk(a2.x, a2.y), cvtpk(a2.z, a2.w), cvtpk(a3.x, a3.y), cvtpk(a3.z, a3.w) };
    *(uint4*)(l) = p0; *(uint4*)(l + 8) = p1;
}
__device__ __forceinline__ void stage8(const float* g, u16* l, bool v) {
    float4 a0, a1;
    const float4 z = make_float4(0.f, 0.f, 0.f, 0.f);
    if (v) { a0 = *(const float4*)(g); a1 = *(const float4*)(g + 4); }
    else   { a0 = z; a1 = z; }
    uint4 p0 = { cvtpk(a0.x, a0.y), cvtpk(a0.z, a0.w), cvtpk(a1.x, a1.y), cvtpk(a1.z, a1.w) };
    *(uint4*)(l) = p0;
}

// ==================== CSR build ====================

__global__ void hist_kernel(const int* __restrict__ recv, int* __restrict__ counts) {
    const int e = blockIdx.x * 256 + threadIdx.x;
    if (e < N_EDGES) atomicAdd(&counts[recv[e]], 1);
}

__global__ __launch_bounds__(256) void scan_k1(const int* __restrict__ counts,
                                               int* __restrict__ rowp,
                                               int* __restrict__ partials) {
    __shared__ int sd[256];
    const int t = threadIdx.x;
    const int base = blockIdx.x * 1024 + t * 4;
    int c0 = 0, c1 = 0, c2 = 0, c3 = 0;
    if (base + 3 < N_NODES) {
        int4 v = *(const int4*)&counts[base];
        c0 = v.x; c1 = v.y; c2 = v.z; c3 = v.w;
    } else {
        if (base     < N_NODES) c0 = counts[base];
        if (base + 1 < N_NODES) c1 = counts[base + 1];
        if (base + 2 < N_NODES) c2 = counts[base + 2];
        if (base + 3 < N_NODES) c3 = counts[base + 3];
    }
    const int T = c0 + c1 + c2 + c3;
    sd[t] = T; __syncthreads();
    for (int off = 1; off < 256; off <<= 1) {
        int v = (t >= off) ? sd[t - off] : 0;
        __syncthreads();
        sd[t] += v;
        __syncthreads();
    }
    const int excl = sd[t] - T;
    if (base     < N_NODES) rowp[base]     = excl;
    if (base + 1 < N_NODES) rowp[base + 1] = excl + c0;
    if (base + 2 < N_NODES) rowp[base + 2] = excl + c0 + c1;
    if (base + 3 < N_NODES) rowp[base + 3] = excl + c0 + c1 + c2;
    if (t == 255) partials[blockIdx.x] = sd[255];
}

__global__ __launch_bounds__(64) void scan_k2(int* __restrict__ partials) {
    __shared__ int sd[64];
    const int t = threadIdx.x;
    const int v0 = (t < NBLK1) ? partials[t] : 0;
    sd[t] = v0; __syncthreads();
    for (int off = 1; off < 64; off <<= 1) {
        int v = (t >= off) ? sd[t - off] : 0;
        __syncthreads();
        sd[t] += v;
        __syncthreads();
    }
    if (t < NBLK1) partials[t] = sd[t] - v0;
}

__global__ __launch_bounds__(256) void scan_k3(int* __restrict__ rowp,
                                               const int* __restrict__ partials,
                                               int* __restrict__ cursors) {
    const int add = partials[blockIdx.x];
    const int base = blockIdx.x * 1024 + threadIdx.x * 4;
    #pragma unroll
    for (int i = 0; i < 4; ++i) {
        const int idx = base + i;
        if (idx < N_NODES) {
            const int v = rowp[idx] + add;
            rowp[idx] = v;
            cursors[idx] = v;
        }
    }
    if (blockIdx.x == 0 && threadIdx.x == 0) rowp[N_NODES] = N_EDGES;
}

// fill + edge-feature permute: sequential reads of e, scattered writes at CSR slot
__global__ void fill_kernel(const int* __restrict__ recv,
                            const int* __restrict__ snd,
                            const float* __restrict__ sef,
                            const float* __restrict__ ev,
                            const float* __restrict__ len,
                            int* __restrict__ cursors,
                            int* __restrict__ esnd,
                            int* __restrict__ ercv,
                            u16* __restrict__ sefp,
                            u16* __restrict__ lenp,
                            float* __restrict__ evp) {
    const int e = blockIdx.x * 256 + threadIdx.x;
    if (e >= N_EDGES) return;
    const int r = recv[e];
    const int pos = atomicAdd(&cursors[r], 1);
    esnd[pos] = snd[e];
    ercv[pos] = r;
    lenp[pos] = f2bf(len[e]);
    const float* ep = ev + (size_t)e * 3;
    float* dp = evp + (size_t)pos * 3;
    dp[0] = ep[0]; dp[1] = ep[1]; dp[2] = ep[2];
    const float* sp = sef + (size_t)e * 32;
    u16* op = sefp + (size_t)pos * 32;
    #pragma unroll
    for (int i = 0; i < 4; ++i) {
        float4 a = ((const float4*)sp)[2 * i];
        float4 b = ((const float4*)sp)[2 * i + 1];
        uint4 p = { cvtpk(a.x, a.y), cvtpk(a.z, a.w), cvtpk(b.x, b.y), cvtpk(b.z, b.w) };
        ((uint4*)op)[i] = p;
    }
}

// ==================== weight pre-conversion: W[k][n] f32 -> Wt[n][k] bf16 ====================

#define WT_TOTAL (128 * W1K + 2 * 128 * 128)

__global__ __launch_bounds__(256)
void wcvt_kernel(const float* __restrict__ W1, const float* __restrict__ W2,
                 const float* __restrict__ W3, u16* __restrict__ wt) {
    const int i = blockIdx.x * 256 + threadIdx.x;
    if (i < 128 * W1K) {
        const int n = i / W1K, k = i - n * W1K;
        wt[i] = (k < 161) ? f2bf(W1[(size_t)k * 128 + n]) : (u16)0;
    } else if (i < 128 * W1K + 128 * 128) {
        const int j = i - 128 * W1K;
        const int n = j >> 7, k = j & 127;
        wt[i] = f2bf(W2[(size_t)k * 128 + n]);
    } else if (i < WT_TOTAL) {
        const int j = i - 128 * W1K - 128 * 128;
        const int n = j >> 7, k = j & 127;
        wt[i] = f2bf(W3[(size_t)k * 128 + n]);
    }
}

// ==================== node feature pre-conversion to bf16 tables ====================

#define NS_ELEMS (N_NODES * 64)
#define NV_ELEMS (N_NODES * 96)

__global__ __launch_bounds__(256)
void nodecvt_kernel(const float* __restrict__ ns, const float* __restrict__ nv,
                    u16* __restrict__ nsb, u16* __restrict__ nvb) {
    const int i2 = (blockIdx.x * 256 + threadIdx.x) * 2;
    if (i2 < NS_ELEMS) {
        float2 v = *(const float2*)(ns + i2);
        *(unsigned*)(nsb + i2) = cvtpk(v.x, v.y);
    } else if (i2 < NS_ELEMS + NV_ELEMS) {
        const int j2 = i2 - NS_ELEMS;
        float2 v = *(const float2*)(nv + j2);
        *(unsigned*)(nvb + j2) = cvtpk(v.x, v.y);
    }
}

// ==================== phase E: MLP (reg-direct A) + piece-major factored msg ====================
// msgT layout: piece p (16B units), row r in [0,cap): msg + ((size_t)p*cap + r)*8 u16.
// pieces 0..3 m0 | 4..11 sg | 12..23 m1b | 24 ev as float4{x,y,z,0}.

__global__ __launch_bounds__(256, 7)
void mlp_msg_kernel(const u16* __restrict__ ns_bf,
                    const u16* __restrict__ nv_bf,
                    const u16* __restrict__ sefp,
                    const u16* __restrict__ lenp,
                    const float* __restrict__ evp,
                    const int* __restrict__ esnd,
                    const int* __restrict__ ercv,
                    const u16* __restrict__ wt,
                    const float* __restrict__ b1,
                    const float* __restrict__ b2,
                    const float* __restrict__ b3,
                    u16* __restrict__ msg, long cap, int slo, int cnt)
{
    __shared__ u16 Hb[EB * HST];

    const int t = threadIdx.x;
    const int lbase = blockIdx.x * EB;
    const int w = t >> 6, l = t & 63;
    const int lr = l & 31, lg = l >> 5;
    const int m0 = (w >> 1) * 32, n0 = (w & 1) * 64;

    // MFMA-role edge (one per lane)
    const int lsA   = (lbase + m0 + lr < cnt) ? (lbase + m0 + lr) : (cnt - 1);
    const int slotA = slo + lsA;
    const int siA = esnd[slotA];
    const int riA = ercv[slotA];

    // epilogue-role edge (4 threads per edge)
    const int me = t >> 2, q = t & 3;
    const int lsE0 = lbase + me;
    const bool veE = lsE0 < cnt;
    const int lsE = veE ? lsE0 : (cnt - 1);
    const int slotE = slo + lsE;
    const int siE = esnd[slotE];

    // ---- layer-1 A fragments: direct global -> registers ----
    bf16x8 afr[11];
    {
        const u16* sp = ns_bf + (size_t)siA * 64 + lg * 8;
        const u16* rp = ns_bf + (size_t)riA * 64 + lg * 8;
        const u16* fp = sefp + (size_t)slotA * 32 + lg * 8;
        #pragma unroll
        for (int ks = 0; ks < 4; ++ks) afr[ks]     = *(const bf16x8*)(sp + ks * 16);
        #pragma unroll
        for (int ks = 0; ks < 4; ++ks) afr[4 + ks] = *(const bf16x8*)(rp + ks * 16);
        afr[8] = *(const bf16x8*)(fp);
        afr[9] = *(const bf16x8*)(fp + 16);
        bf16x8 z = (bf16x8)0;
        if (lg == 0) z[0] = (short)lenp[slotA];
        afr[10] = z;
    }

    const u16* w1t = wt;
    const u16* w2t = wt + 128 * W1K;
    const u16* w3t = w2t + 128 * 128;

    f32x16 acc0, acc1;

    // ---------- layer 1 (A from registers, B streamed from global/L2) ----------
    #pragma unroll
    for (int i = 0; i < 16; ++i) { acc0[i] = 0.f; acc1[i] = 0.f; }
    {
        const u16* bp0 = w1t + (size_t)(n0 + lr) * W1K + lg * 8;
        const u16* bp1 = bp0 + 32 * W1K;
        #pragma unroll
        for (int ks = 0; ks < 11; ++ks) {
            bf16x8 bv0 = *(const bf16x8*)(bp0 + ks * 16);
            bf16x8 bv1 = *(const bf16x8*)(bp1 + ks * 16);
            acc0 = __builtin_amdgcn_mfma_f32_32x32x16_bf16(afr[ks], bv0, acc0, 0, 0, 0);
            acc1 = __builtin_amdgcn_mfma_f32_32x32x16_bf16(afr[ks], bv1, acc1, 0, 0, 0);
        }
    }
    {   const float bv0 = b1[n0 + lr], bv1 = b1[n0 + 32 + lr];
        #pragma unroll
        for (int r = 0; r < 16; ++r) {
            const int row = (r & 3) + 8 * (r >> 2) + 4 * lg;
            Hb[(m0 + row) * HST + n0 + lr]      = f2bf(fsilu(acc0[r] + bv0));
            Hb[(m0 + row) * HST + n0 + 32 + lr] = f2bf(fsilu(acc1[r] + bv1));
        }
    }
    __syncthreads();

    auto run_layer_lds = [&](const u16* Wg, f32x16& a0, f32x16& a1) {
        #pragma unroll
        for (int i = 0; i < 16; ++i) { a0[i] = 0.f; a1[i] = 0.f; }
        const u16* ap  = Hb + (m0 + lr) * HST + lg * 8;
        const u16* bp0 = Wg + (size_t)(n0 + lr) * 128 + lg * 8;
        const u16* bp1 = bp0 + 32 * 128;
        #pragma unroll
        for (int ks = 0; ks < 8; ++ks) {
            bf16x8 af  = *(const bf16x8*)(ap  + ks * 16);
            bf16x8 bv0 = *(const bf16x8*)(bp0 + ks * 16);
            bf16x8 bv1 = *(const bf16x8*)(bp1 + ks * 16);
            a0 = __builtin_amdgcn_mfma_f32_32x32x16_bf16(af, bv0, a0, 0, 0, 0);
            a1 = __builtin_amdgcn_mfma_f32_32x32x16_bf16(af, bv1, a1, 0, 0, 0);
        }
    };

    // ---------- layer 2 ----------
    run_layer_lds(w2t, acc0, acc1);
    __syncthreads();
    {   const float bv0 = b2[n0 + lr], bv1 = b2[n0 + 32 + lr];
        #pragma unroll
        for (int r = 0; r < 16; ++r) {
            const int row = (r & 3) + 8 * (r >> 2) + 4 * lg;
            Hb[(m0 + row) * HST + n0 + lr]      = f2bf(fsilu(acc0[r] + bv0));
            Hb[(m0 + row) * HST + n0 + 32 + lr] = f2bf(fsilu(acc1[r] + bv1));
        }
    }
    __syncthreads();

    // ---------- layer 3 (mix) ----------
    run_layer_lds(w3t, acc0, acc1);
    __syncthreads();
    {   const float bv0 = b3[n0 + lr], bv1 = b3[n0 + 32 + lr];
        #pragma unroll
        for (int r = 0; r < 16; ++r) {
            const int row = (r & 3) + 8 * (r >> 2) + 4 * lg;
            Hb[(m0 + row) * HST + n0 + lr]      = f2bf(acc0[r] + bv0);
            Hb[(m0 + row) * HST + n0 + 32 + lr] = f2bf(acc1[r] + bv1);
        }
    }
    __syncthreads();

    // ---------- factored message epilogue: 4 threads/edge, piece-major writes ----------
    if (veE) {
        const u16* Hr = Hb + me * HST;
        const float evx = evp[(size_t)slotE * 3 + 0];
        const float evy = evp[(size_t)slotE * 3 + 1];
        const float evz = evp[(size_t)slotE * 3 + 2];

        auto pp = [&](int p) { return msg + ((size_t)p * cap + lsE) * 8; };

        // sender scalars k=16q..16q+15 and vectors c=8q..8q+7 direct from global
        u16 sa[16], va[24];
        {
            const u16* nsrow = ns_bf + (size_t)siE * 64 + 16 * q;
            *(u16x8*)(sa)     = *(const u16x8*)(nsrow);
            *(u16x8*)(sa + 8) = *(const u16x8*)(nsrow + 8);
            const u16* nvrow = nv_bf + (size_t)siE * 96 + 24 * q;
            *(u16x8*)(va)      = *(const u16x8*)(nvrow);
            *(u16x8*)(va + 8)  = *(const u16x8*)(nvrow + 8);
            *(u16x8*)(va + 16) = *(const u16x8*)(nvrow + 16);
        }

        float m0v[8], m1bv[24];
        #pragma unroll
        for (int j = 0; j < 8; ++j) {
            const int c = 8 * q + j;
            const float vx = bf2f(va[3 * j]), vy = bf2f(va[3 * j + 1]), vz = bf2f(va[3 * j + 2]);
            m0v[j] = (vx * evx + vy * evy + vz * evz) * INV_SQ3 * bf2f(Hr[c]);
            const float gb = bf2f(Hr[96 + c]) * INV_SQ2;
            m1bv[3 * j + 0] = (vy * evz - vz * evy) * gb;
            m1bv[3 * j + 1] = (vz * evx - vx * evz) * gb;
            m1bv[3 * j + 2] = (vx * evy - vy * evx) * gb;
        }
        {   uint4 o = { cvtpk(m0v[0], m0v[1]), cvtpk(m0v[2], m0v[3]),
                        cvtpk(m0v[4], m0v[5]), cvtpk(m0v[6], m0v[7]) };
            *(uint4*)pp(q) = o;
        }
        {   uint4 o0 = { cvtpk(m1bv[0],  m1bv[1]),  cvtpk(m1bv[2],  m1bv[3]),
                         cvtpk(m1bv[4],  m1bv[5]),  cvtpk(m1bv[6],  m1bv[7])  };
            uint4 o1 = { cvtpk(m1bv[8],  m1bv[9]),  cvtpk(m1bv[10], m1bv[11]),
                         cvtpk(m1bv[12], m1bv[13]), cvtpk(m1bv[14], m1bv[15]) };
            uint4 o2 = { cvtpk(m1bv[16], m1bv[17]), cvtpk(m1bv[18], m1bv[19]),
                         cvtpk(m1bv[20], m1bv[21]), cvtpk(m1bv[22], m1bv[23]) };
            *(uint4*)pp(12 + 3 * q) = o0;
            *(uint4*)pp(13 + 3 * q) = o1;
            *(uint4*)pp(14 + 3 * q) = o2;
        }
        {   float sg[16];
            #pragma unroll
            for (int j = 0; j < 16; ++j) {
                const int k = 16 * q + j;
                sg[j] = bf2f(sa[j]) * bf2f(Hr[32 + k]);
            }
            uint4 o0 = { cvtpk(sg[0],  sg[1]),  cvtpk(sg[2],  sg[3]),
                         cvtpk(sg[4],  sg[5]),  cvtpk(sg[6],  sg[7])  };
            uint4 o1 = { cvtpk(sg[8],  sg[9]),  cvtpk(sg[10], sg[11]),
                         cvtpk(sg[12], sg[13]), cvtpk(sg[14], sg[15]) };
            *(uint4*)pp(4 + 2 * q) = o0;
            *(uint4*)pp(5 + 2 * q) = o1;
        }
        if (q == 0) {
            uint4 e4 = { __builtin_bit_cast(unsigned, evx),
                         __builtin_bit_cast(unsigned, evy),
                         __builtin_bit_cast(unsigned, evz), 0u };
            *(uint4*)pp(24) = e4;
        }
    }
}

// ==================== phase 2: paired streaming gather, piece-major msg ====================

__global__ __launch_bounds__(256)
void msg_gather_seq(const int* __restrict__ rowp,
                    const u16* __restrict__ msg, long cap,
                    float* __restrict__ out,
                    int slo, int shi, int first)
{
    __shared__ float oacc[4][OUTC];

    const int gw = (blockIdx.x * 256 + threadIdx.x) >> 6;   // node
    const int l  = threadIdx.x & 63;
    const bool nvalid = gw < N_NODES;

    const int rp0 = nvalid ? rowp[gw] : 0;
    const int rp1 = nvalid ? rowp[gw + 1] : 0;
    const int lo = rp0 > slo ? rp0 : slo;
    const int hi = rp1 < shi ? rp1 : shi;
    const int n  = hi > lo ? hi - lo : 0;

    const int half = (l >= 26) ? 1 : 0;
    const int sl   = l - 26 * half;
    const bool lact = (l < 52) && (sl < 24);
    const int seg  = (sl < 4) ? 0 : (sl < 12 ? 1 : 2);

    float acc[24];
    #pragma unroll
    for (int i = 0; i < 24; ++i) acc[i] = 0.f;

    const long r0 = lo - slo;
    const u16* pbase  = msg + ((size_t)sl * cap + r0) * 8;
    const u16* evbase = msg + ((size_t)24 * cap + r0) * 8;

    auto body = [&](int row) {
        const u16x8 v = *(const u16x8*)(pbase + (size_t)row * 8);
        if (seg == 1) {
            const float4 e4 = *(const float4*)(evbase + (size_t)row * 8);
            #pragma unroll
            for (int i = 0; i < 8; ++i) {
                const float s = bf2f(v[i]);
                acc[3 * i + 0] += s * e4.x;
                acc[3 * i + 1] += s * e4.y;
                acc[3 * i + 2] += s * e4.z;
            }
        } else {
            #pragma unroll
            for (int i = 0; i < 8; ++i) acc[i] += bf2f(v[i]);
        }
    };

    int j = 0;
    for (; j + 4 <= n; j += 4) {
        if (lact) { body(j + half); body(j + 2 + half); }
    }
    for (; j + 2 <= n; j += 2) {
        if (lact) body(j + half);
    }
    if (j < n && half == 0 && lact) body(j);

    float* oa = oacc[(threadIdx.x >> 6)];

    if (half == 0 && lact) {
        if (seg == 0) {
            #pragma unroll
            for (int i = 0; i < 8; ++i) oa[sl * 8 + i] = acc[i];
        } else if (seg == 1) {
            const int k0 = (sl - 4) * 8;
            #pragma unroll
            for (int i = 0; i < 8; ++i) {
                oa[32 + 3 * (k0 + i) + 0] = acc[3 * i + 0];
                oa[32 + 3 * (k0 + i) + 1] = acc[3 * i + 1];
                oa[32 + 3 * (k0 + i) + 2] = acc[3 * i + 2];
            }
        } else {
            const int c0 = (sl - 12) * 8;
            #pragma unroll
            for (int i = 0; i < 8; ++i) oa[224 + c0 + i] = acc[i];
        }
    }
    __syncthreads();
    if (half == 1 && lact) {
        if (seg == 0) {
            #pragma unroll
            for (int i = 0; i < 8; ++i) oa[sl * 8 + i] += acc[i];
        } else if (seg == 1) {
            const int k0 = (sl - 4) * 8;
            #pragma unroll
            for (int i = 0; i < 8; ++i) {
                oa[32 + 3 * (k0 + i) + 0] += acc[3 * i + 0];
                oa[32 + 3 * (k0 + i) + 1] += acc[3 * i + 1];
                oa[32 + 3 * (k0 + i) + 2] += acc[3 * i + 2];
            }
        } else {
            const int c0 = (sl - 12) * 8;
            #pragma unroll
            for (int i = 0; i < 8; ++i) oa[224 + c0 + i] += acc[i];
        }
    }
    __syncthreads();

    if (nvalid && l < 40) {
        float r[8];
        #pragma unroll
        for (int i = 0; i < 8; ++i) r[i] = oa[l * 8 + i] * INV_AVG;
        float* orow = out + (size_t)gw * OUTC + l * 8;
        if (first) {
            *(float4*)(orow)     = make_float4(r[0], r[1], r[2], r[3]);
            *(float4*)(orow + 4) = make_float4(r[4], r[5], r[6], r[7]);
        } else if (n > 0) {
            float4 p0 = *(const float4*)(orow);
            float4 p1 = *(const float4*)(orow + 4);
            p0.x += r[0]; p0.y += r[1]; p0.z += r[2]; p0.w += r[3];
            p1.x += r[4]; p1.y += r[5]; p1.z += r[6]; p1.w += r[7];
            *(float4*)(orow)     = p0;
            *(float4*)(orow + 4) = p1;
        }
    }
}

// ==================== last-resort fallback: atomic fused ====================

__global__ __launch_bounds__(256, 2)
void fused_mpconv_atomic(const float* __restrict__ node_scalars,
                         const float* __restrict__ node_vectors,
                         const float* __restrict__ edge_vec,
                         const float* __restrict__ sef,
                         const float* __restrict__ lengths,
                         const int* __restrict__ senders,
                         const int* __restrict__ receivers,
                         const float* __restrict__ W1, const float* __restrict__ b1,
                         const float* __restrict__ W2, const float* __restrict__ b2,
                         const float* __restrict__ W3, const float* __restrict__ b3,
                         float* __restrict__ out)
{
    __shared__ u16 A [EB * KP1];
    __shared__ u16 VS[EB * KV];
    __shared__ u16 Hb[EB * KH];
    __shared__ u16 Wt[2][128 * WTS];
    __shared__ float evl[3][EB];
    __shared__ int sidx[EB], ridx[EB];

    const int t = threadIdx.x;
    const int ebase = blockIdx.x * EB;

    {   const int e = t & 63, sub = t >> 6;
        const int eg = ebase + e; const bool ve = eg < N_EDGES;
        if (sub == 0)      sidx[e] = ve ? senders[eg] : 0;
        else if (sub == 1) ridx[e] = ve ? receivers[eg] : 0;
        else if (sub == 2) {
            evl[0][e] = ve ? edge_vec[(size_t)eg * 3 + 0] : 0.f;
            evl[1][e] = ve ? edge_vec[(size_t)eg * 3 + 1] : 0.f;
            evl[2][e] = ve ? edge_vec[(size_t)eg * 3 + 2] : 0.f;
        }
    }
    __syncthreads();

    {   const int me = t >> 2, q = t & 3;
        const int eg = ebase + me; const bool ve = eg < N_EDGES;
        const int si = sidx[me], ri = ridx[me];
        u16* Ar = A + me * KP1;
        stage16(node_scalars + (size_t)si * 64 + q * 16, Ar + q * 16,       ve);
        stage16(node_scalars + (size_t)ri * 64 + q * 16, Ar + 64 + q * 16,  ve);
        stage8 (sef          + (size_t)eg * 32 + q * 8,  Ar + 128 + q * 8,  ve);
        u16x8 zz = (u16x8)0;
        *(u16x8*)(Ar + 160 + q * 8) = zz;
        if (q == 0) *(u16x8*)(Ar + 192) = zz;
        stage16(node_vectors + (size_t)si * 96 + q * 24,      VS + me * KV + q * 24,      ve);
        stage8 (node_vectors + (size_t)si * 96 + q * 24 + 16, VS + me * KV + q * 24 + 16, ve);
        if (q == 0) Ar[160] = f2bf(ve ? lengths[eg] : 0.f);
    }
    __syncthreads();

    const int w  = t >> 6, l = t & 63;
    const int lr = l & 31;
    const int lg = l >> 5;
    const int m0 = (w >> 1) * 32;
    const int n0 = (w & 1) * 64;

    f32x16 acc0, acc1;
    const int n  = t & 127, ph = t >> 7;

    auto run_layer = [&](const u16* Asrc, int astr, const float* Wg, int Kr, int nsteps,
                         f32x16& a0, f32x16& a1) {
        #pragma unroll
        for (int i = 0; i < 16; ++i) { a0[i] = 0.f; a1[i] = 0.f; }
        #pragma unroll
        for (int i = 0; i < 4; ++i) {
            int kl = (i * 2 + ph) * 2;
            float v0 = (kl     < Kr) ? Wg[(size_t)kl * 128 + n]       : 0.f;
            float v1 = (kl + 1 < Kr) ? Wg[(size_t)(kl + 1) * 128 + n] : 0.f;
            *(unsigned*)&Wt[0][n * WTS + kl] = cvtpk(v0, v1);
        }
        __syncthreads();
        const u16* ap = Asrc + (m0 + lr) * astr + lg * 8;
        for (int ks = 0; ks < nsteps; ++ks) {
            const int cur = ks & 1;
            float v0[4], v1[4];
            const int kb = (ks + 1) * 16;
            if (ks + 1 < nsteps) {
                #pragma unroll
                for (int i = 0; i < 4; ++i) {
                    int kg = kb + (i * 2 + ph) * 2;
                    v0[i] = (kg     < Kr) ? Wg[(size_t)kg * 128 + n]       : 0.f;
                    v1[i] = (kg + 1 < Kr) ? Wg[(size_t)(kg + 1) * 128 + n] : 0.f;
                }
            }
            bf16x8 af = *(const bf16x8*)(ap + ks * 16);
            bf16x8 bf0 = *(const bf16x8*)(&Wt[cur][(n0      + lr) * WTS + lg * 8]);
            bf16x8 bf1 = *(const bf16x8*)(&Wt[cur][(n0 + 32 + lr) * WTS + lg * 8]);
            a0 = __builtin_amdgcn_mfma_f32_32x32x16_bf16(af, bf0, a0, 0, 0, 0);
            a1 = __builtin_amdgcn_mfma_f32_32x32x16_bf16(af, bf1, a1, 0, 0, 0);
            if (ks + 1 < nsteps) {
                #pragma unroll
                for (int i = 0; i < 4; ++i) {
                    int kl = (i * 2 + ph) * 2;
                    *(unsigned*)&Wt[cur ^ 1][n * WTS + kl] = cvtpk(v0[i], v1[i]);
                }
            }
            __syncthreads();
        }
    };

    run_layer(A, KP1, W1, 161, 11, acc0, acc1);
    {   const float bv0 = b1[n0 + lr], bv1 = b1[n0 + 32 + lr];
        #pragma unroll
        for (int r = 0; r < 16; ++r) {
            const int row = (r & 3) + 8 * (r >> 2) + 4 * lg;
            Hb[(m0 + row) * KH + n0 + lr]      = f2bf(fsilu(acc0[r] + bv0));
            Hb[(m0 + row) * KH + n0 + 32 + lr] = f2bf(fsilu(acc1[r] + bv1));
        }
    }
    __syncthreads();

    run_layer(Hb, KH, W2, 128, 8, acc0, acc1);
    __syncthreads();
    {   const float bv0 = b2[n0 + lr], bv1 = b2[n0 + 32 + lr];
        #pragma unroll
        for (int r = 0; r < 16; ++r) {
            const int row = (r & 3) + 8 * (r >> 2) + 4 * lg;
            Hb[(m0 + row) * KH + n0 + lr]      = f2bf(fsilu(acc0[r] + bv0));
            Hb[(m0 + row) * KH + n0 + 32 + lr] = f2bf(fsilu(acc1[r] + bv1));
        }
    }
    __syncthreads();

    run_layer(Hb, KH, W3, 128, 8, acc0, acc1);
    __syncthreads();
    {   const float bv0 = b3[n0 + lr], bv1 = b3[n0 + 32 + lr];
        #pragma unroll
        for (int r = 0; r < 16; ++r) {
            const int row = (r & 3) + 8 * (r >> 2) + 4 * lg;
            Hb[(m0 + row) * KH + n0 + lr]      = f2bf(acc0[r] + bv0);
            Hb[(m0 + row) * KH + n0 + 32 + lr] = f2bf(acc1[r] + bv1);
        }
    }
    __syncthreads();

    {   const int me = t >> 2, r = t & 3;
        const int eg2 = ebase + me;
        if (eg2 < N_EDGES) {
            const int row = ridx[me];
            const float evx = evl[0][me], evy = evl[1][me], evz = evl[2][me];
            float* orow = out + (size_t)row * OUTC;
            const u16* Ar = A  + me * KP1;
            const u16* Vr = VS + me * KV;
            const u16* Hr = Hb + me * KH;
            for (int col = r; col < OUTC; col += 4) {
                float val;
                if (col < 32) {
                    const int c = col;
                    const float vx = bf2f(Vr[3 * c]), vy = bf2f(Vr[3 * c + 1]), vz = bf2f(Vr[3 * c + 2]);
                    val = (vx * evx + vy * evy + vz * evz) * INV_SQ3 * bf2f(Hr[c]);
                } else {
                    const int idx = col - 32;
                    const int k = idx / 3;
                    const int d = idx - 3 * k;
                    const float g = bf2f(Hr[32 + k]);
                    if (k < 64) {
                        const float evd = (d == 0) ? evx : ((d == 1) ? evy : evz);
                        val = bf2f(Ar[k]) * evd * g;
                    } else {
                        const int c = k - 64;
                        const float vx = bf2f(Vr[3 * c]), vy = bf2f(Vr[3 * c + 1]), vz = bf2f(Vr[3 * c + 2]);
                        float cr;
                        if (d == 0)      cr = vy * evz - vz * evy;
                        else if (d == 1) cr = vz * evx - vx * evz;
                        else             cr = vx * evy - vy * evx;
                        val = cr * INV_SQ2 * g;
                    }
                }
                atomicAdd(&orow[col], val * INV_AVG);
            }
        }
    }
}

// ==================== launch ====================

extern "C" void kernel_launch(void* const* d_in, const int* in_sizes, int n_in,
                              void* d_out, int out_size, void* d_ws, size_t ws_size,
                              hipStream_t stream) {
    (void)in_sizes; (void)n_in;
    const float* node_scalars = (const float*)d_in[0];
    const float* node_vectors = (const float*)d_in[1];
    const float* edge_vec     = (const float*)d_in[2];
    const float* sef          = (const float*)d_in[3];
    const float* lengths      = (const float*)d_in[4];
    const int*   senders      = (const int*)d_in[5];
    const int*   receivers    = (const int*)d_in[6];
    const float* W1 = (const float*)d_in[7];
    const float* b1 = (const float*)d_in[8];
    const float* W2 = (const float*)d_in[9];
    const float* b2 = (const float*)d_in[10];
    const float* W3 = (const float*)d_in[11];
    const float* b3 = (const float*)d_in[12];
    float* out = (float*)d_out;

    auto align256 = [](size_t x) { return (x + 255) & ~(size_t)255; };

    size_t off = 0;
    const size_t o_counts  = off; off += align256((size_t)N_NODES * sizeof(int));
    const size_t o_rowp    = off; off += align256((size_t)(N_NODES + 1) * sizeof(int));
    const size_t o_cursors = off; off += align256((size_t)(N_NODES + 1) * sizeof(int));
    const size_t o_part    = off; off += align256(64 * sizeof(int));
    const size_t o_esnd    = off; off += align256((size_t)N_EDGES * sizeof(int));
    const size_t o_ercv    = off; off += align256((size_t)N_EDGES * sizeof(int));
    const size_t o_wt      = off; off += align256((size_t)WT_TOTAL * sizeof(u16));
    const size_t o_nsb     = off; off += align256((size_t)NS_ELEMS * sizeof(u16));
    const size_t o_nvb     = off; off += align256((size_t)NV_ELEMS * sizeof(u16));
    const size_t o_sefp    = off; off += align256((size_t)N_EDGES * 32 * sizeof(u16));
    const size_t o_lenp    = off; off += align256((size_t)N_EDGES * sizeof(u16));
    const size_t o_evp     = off; off += align256((size_t)N_EDGES * 3 * sizeof(float));
    const size_t o_msg     = off;
    const size_t fixed_bytes = off;

    const size_t ROWB = (size_t)NPIECE * 16;   // 400 B per edge across pieces
    long Ec = 0;
    if (ws_size > fixed_bytes + (size_t)128 * ROWB) {
        size_t cap_rows = (ws_size - fixed_bytes) / ROWB;
        Ec = ((long)cap_rows - 64) / 64 * 64;
        if (Ec > N_EDGES) Ec = N_EDGES;
    }

    char* ws = (char*)d_ws;

    if (Ec >= 64) {
        int* counts  = (int*)(ws + o_counts);
        int* rowp    = (int*)(ws + o_rowp);
        int* cursors = (int*)(ws + o_cursors);
        int* part    = (int*)(ws + o_part);
        int* esnd    = (int*)(ws + o_esnd);
        int* ercv    = (int*)(ws + o_ercv);
        u16* wt      = (u16*)(ws + o_wt);
        u16* nsb     = (u16*)(ws + o_nsb);
        u16* nvb     = (u16*)(ws + o_nvb);
        u16* sefp    = (u16*)(ws + o_sefp);
        u16* lenp    = (u16*)(ws + o_lenp);
        float* evp   = (float*)(ws + o_evp);
        u16* msg     = (u16*)(ws + o_msg);

        hipMemsetAsync(counts, 0, (size_t)N_NODES * sizeof(int), stream);
        hist_kernel<<<(N_EDGES + 255) / 256, 256, 0, stream>>>(receivers, counts);
        scan_k1<<<NBLK1, 256, 0, stream>>>(counts, rowp, part);
        scan_k2<<<1, 64, 0, stream>>>(part);
        scan_k3<<<NBLK1, 256, 0, stream>>>(rowp, part, cursors);
        fill_kernel<<<(N_EDGES + 255) / 256, 256, 0, stream>>>(
            receivers, senders, sef, edge_vec, lengths,
            cursors, esnd, ercv, sefp, lenp, evp);
        wcvt_kernel<<<(WT_TOTAL + 255) / 256, 256, 0, stream>>>(W1, W2, W3, wt);
        {
            const int tot2 = (NS_ELEMS + NV_ELEMS) / 2;
            nodecvt_kernel<<<(tot2 + 255) / 256, 256, 0, stream>>>(
                node_scalars, node_vectors, nsb, nvb);
        }

        const int nchunks = (int)((N_EDGES + Ec - 1) / Ec);
        const int ggrid = (N_NODES * 64 + 255) / 256;
        for (int c = 0; c < nchunks; ++c) {
            const int slo = (int)(c * Ec);
            const int cnt = (int)((N_EDGES - slo < Ec) ? (N_EDGES - slo) : Ec);
            mlp_msg_kernel<<<(cnt + EB - 1) / EB, 256, 0, stream>>>(
                nsb, nvb, sefp, lenp, evp, esnd, ercv,
                wt, b1, b2, b3, msg, Ec, slo, cnt);
            msg_gather_seq<<<ggrid, 256, 0, stream>>>(
                rowp, msg, Ec, out, slo, slo + cnt, c == 0 ? 1 : 0);
        }
    } else {
        hipMemsetAsync(out, 0, (size_t)out_size * sizeof(float), stream);
        fused_mpconv_atomic<<<(N_EDGES + EB - 1) / EB, 256, 0, stream>>>(
            node_scalars, node_vectors, edge_vec, sef, lengths,
            senders, receivers, W1, b1, W2, b2, W3, b3, out);
    }
}

// Round 15
// 411.092 us; speedup vs baseline: 1.2092x; 1.2092x over previous
//
#include <hip/hip_runtime.h>

#define N_NODES 50000
#define N_EDGES 500000
#define EB 64
#define HST 136          // Hb row stride (u16): cols 0..127 data, 128..135 pad
#define W1K 176          // W1t row length (k padded 161->176, zeros beyond 160)
#define OUTC 320
#define MROW 208         // msg row: [m0 32 | sg 64 | m1b 96 | ev 3xf32=6 | pad] u16 = 416B
#define NBLK1 49
// fallback-kernel layout constants
#define KP1 200
#define KH  136
#define KV  104
#define WTS 40
#define INV_SQ3 0.57735026918962576f
#define INV_SQ2 0.70710678118654752f
#define INV_AVG 0.1f

typedef short bf16x8 __attribute__((ext_vector_type(8)));
typedef unsigned short u16;
typedef u16 u16x8 __attribute__((ext_vector_type(8)));
typedef float f32x16 __attribute__((ext_vector_type(16)));

__device__ __forceinline__ unsigned cvtpk(float lo, float hi) {
    unsigned r;
    asm("v_cvt_pk_bf16_f32 %0, %1, %2" : "=v"(r) : "v"(lo), "v"(hi));
    return r;
}
__device__ __forceinline__ u16 f2bf(float f) { return (u16)cvtpk(f, f); }
__device__ __forceinline__ float bf2f(u16 h) {
    union { unsigned u; float f; } x; x.u = ((unsigned)h) << 16; return x.f;
}
__device__ __forceinline__ float fsilu(float x) {
    return x * __builtin_amdgcn_rcpf(1.f + __expf(-x));
}

__device__ __forceinline__ void stage16(const float* g, u16* l, bool v) {
    float4 a0, a1, a2, a3;
    const float4 z = make_float4(0.f, 0.f, 0.f, 0.f);
    if (v) { a0 = *(const float4*)(g);     a1 = *(const float4*)(g + 4);
             a2 = *(const float4*)(g + 8); a3 = *(const float4*)(g + 12); }
    else   { a0 = z; a1 = z; a2 = z; a3 = z; }
    uint4 p0 = { cvtpk(a0.x, a0.y), cvtpk(a0.z, a0.w), cvtpk(a1.x, a1.y), cvtpk(a1.z, a1.w) };
    uint4 p1 = { cvtpk(a2.x, a2.y), cvtpk(a2.z, a2.w), cvtpk(a3.x, a3.y), cvtpk(a3.z, a3.w) };
    *(uint4*)(l) = p0; *(uint4*)(l + 8) = p1;
}
__device__ __forceinline__ void stage8(const float* g, u16* l, bool v) {
    float4 a0, a1;
    const float4 z = make_float4(0.f, 0.f, 0.f, 0.f);
    if (v) { a0 = *(const float4*)(g); a1 = *(const float4*)(g + 4); }
    else   { a0 = z; a1 = z; }
    uint4 p0 = { cvtpk(a0.x, a0.y), cvtpk(a0.z, a0.w), cvtpk(a1.x, a1.y), cvtpk(a1.z, a1.w) };
    *(uint4*)(l) = p0;
}

// ==================== CSR build ====================

__global__ void hist_kernel(const int* __restrict__ recv, int* __restrict__ counts) {
    const int e = blockIdx.x * 256 + threadIdx.x;
    if (e < N_EDGES) atomicAdd(&counts[recv[e]], 1);
}

__global__ __launch_bounds__(256) void scan_k1(const int* __restrict__ counts,
                                               int* __restrict__ rowp,
                                               int* __restrict__ partials) {
    __shared__ int sd[256];
    const int t = threadIdx.x;
    const int base = blockIdx.x * 1024 + t * 4;
    int c0 = 0, c1 = 0, c2 = 0, c3 = 0;
    if (base + 3 < N_NODES) {
        int4 v = *(const int4*)&counts[base];
        c0 = v.x; c1 = v.y; c2 = v.z; c3 = v.w;
    } else {
        if (base     < N_NODES) c0 = counts[base];
        if (base + 1 < N_NODES) c1 = counts[base + 1];
        if (base + 2 < N_NODES) c2 = counts[base + 2];
        if (base + 3 < N_NODES) c3 = counts[base + 3];
    }
    const int T = c0 + c1 + c2 + c3;
    sd[t] = T; __syncthreads();
    for (int off = 1; off < 256; off <<= 1) {
        int v = (t >= off) ? sd[t - off] : 0;
        __syncthreads();
        sd[t] += v;
        __syncthreads();
    }
    const int excl = sd[t] - T;
    if (base     < N_NODES) rowp[base]     = excl;
    if (base + 1 < N_NODES) rowp[base + 1] = excl + c0;
    if (base + 2 < N_NODES) rowp[base + 2] = excl + c0 + c1;
    if (base + 3 < N_NODES) rowp[base + 3] = excl + c0 + c1 + c2;
    if (t == 255) partials[blockIdx.x] = sd[255];
}

__global__ __launch_bounds__(64) void scan_k2(int* __restrict__ partials) {
    __shared__ int sd[64];
    const int t = threadIdx.x;
    const int v0 = (t < NBLK1) ? partials[t] : 0;
    sd[t] = v0; __syncthreads();
    for (int off = 1; off < 64; off <<= 1) {
        int v = (t >= off) ? sd[t - off] : 0;
        __syncthreads();
        sd[t] += v;
        __syncthreads();
    }
    if (t < NBLK1) partials[t] = sd[t] - v0;
}

__global__ __launch_bounds__(256) void scan_k3(int* __restrict__ rowp,
                                               const int* __restrict__ partials,
                                               int* __restrict__ cursors) {
    const int add = partials[blockIdx.x];
    const int base = blockIdx.x * 1024 + threadIdx.x * 4;
    #pragma unroll
    for (int i = 0; i < 4; ++i) {
        const int idx = base + i;
        if (idx < N_NODES) {
            const int v = rowp[idx] + add;
            rowp[idx] = v;
            cursors[idx] = v;
        }
    }
    if (blockIdx.x == 0 && threadIdx.x == 0) rowp[N_NODES] = N_EDGES;
}

// fill + edge-feature permute: sequential reads of e, scattered writes at CSR slot
__global__ void fill_kernel(const int* __restrict__ recv,
                            const int* __restrict__ snd,
                            const float* __restrict__ sef,
                            const float* __restrict__ ev,
                            const float* __restrict__ len,
                            int* __restrict__ cursors,
                            int* __restrict__ esnd,
                            int* __restrict__ ercv,
                            u16* __restrict__ sefp,
                            u16* __restrict__ lenp,
                            float* __restrict__ evp) {
    const int e = blockIdx.x * 256 + threadIdx.x;
    if (e >= N_EDGES) return;
    const int r = recv[e];
    const int pos = atomicAdd(&cursors[r], 1);
    esnd[pos] = snd[e];
    ercv[pos] = r;
    lenp[pos] = f2bf(len[e]);
    const float* ep = ev + (size_t)e * 3;
    float* dp = evp + (size_t)pos * 3;
    dp[0] = ep[0]; dp[1] = ep[1]; dp[2] = ep[2];
    const float* sp = sef + (size_t)e * 32;
    u16* op = sefp + (size_t)pos * 32;
    #pragma unroll
    for (int i = 0; i < 4; ++i) {
        float4 a = ((const float4*)sp)[2 * i];
        float4 b = ((const float4*)sp)[2 * i + 1];
        uint4 p = { cvtpk(a.x, a.y), cvtpk(a.z, a.w), cvtpk(b.x, b.y), cvtpk(b.z, b.w) };
        ((uint4*)op)[i] = p;
    }
}

// ==================== weight pre-conversion: W[k][n] f32 -> Wt[n][k] bf16 ====================

#define WT_TOTAL (128 * W1K + 2 * 128 * 128)

__global__ __launch_bounds__(256)
void wcvt_kernel(const float* __restrict__ W1, const float* __restrict__ W2,
                 const float* __restrict__ W3, u16* __restrict__ wt) {
    const int i = blockIdx.x * 256 + threadIdx.x;
    if (i < 128 * W1K) {
        const int n = i / W1K, k = i - n * W1K;
        wt[i] = (k < 161) ? f2bf(W1[(size_t)k * 128 + n]) : (u16)0;
    } else if (i < 128 * W1K + 128 * 128) {
        const int j = i - 128 * W1K;
        const int n = j >> 7, k = j & 127;
        wt[i] = f2bf(W2[(size_t)k * 128 + n]);
    } else if (i < WT_TOTAL) {
        const int j = i - 128 * W1K - 128 * 128;
        const int n = j >> 7, k = j & 127;
        wt[i] = f2bf(W3[(size_t)k * 128 + n]);
    }
}

// ==================== node feature pre-conversion to bf16 tables ====================

#define NS_ELEMS (N_NODES * 64)
#define NV_ELEMS (N_NODES * 96)

__global__ __launch_bounds__(256)
void nodecvt_kernel(const float* __restrict__ ns, const float* __restrict__ nv,
                    u16* __restrict__ nsb, u16* __restrict__ nvb) {
    const int i2 = (blockIdx.x * 256 + threadIdx.x) * 2;
    if (i2 < NS_ELEMS) {
        float2 v = *(const float2*)(ns + i2);
        *(unsigned*)(nsb + i2) = cvtpk(v.x, v.y);
    } else if (i2 < NS_ELEMS + NV_ELEMS) {
        const int j2 = i2 - NS_ELEMS;
        float2 v = *(const float2*)(nv + j2);
        *(unsigned*)(nvb + j2) = cvtpk(v.x, v.y);
    }
}

// ==================== phase E: MLP (reg-direct A) + factored msg, CSR-slot order ====================
// LDS = Hb only (17408 B); launch_bounds(256,5) -> 5 blocks/CU.
// NOTE: 5 (not 7) blocks/CU is deliberate — at 7, concurrent random node-row reads +
// dirty msg lines thrash the 32MB L2 (r12: FETCH 290MB, WRITE 360MB vs r9: 130/202).
// msg row [MROW=208 u16]: [0,32) m0 | [32,96) sg | [96,192) m1b | [192,198) ev f32x3 | pad

__global__ __launch_bounds__(256, 5)
void mlp_msg_kernel(const u16* __restrict__ ns_bf,
                    const u16* __restrict__ nv_bf,
                    const u16* __restrict__ sefp,
                    const u16* __restrict__ lenp,
                    const float* __restrict__ evp,
                    const int* __restrict__ esnd,
                    const int* __restrict__ ercv,
                    const u16* __restrict__ wt,
                    const float* __restrict__ b1,
                    const float* __restrict__ b2,
                    const float* __restrict__ b3,
                    u16* __restrict__ msg, int slo, int cnt)
{
    __shared__ u16 Hb[EB * HST];

    const int t = threadIdx.x;
    const int lbase = blockIdx.x * EB;
    const int w = t >> 6, l = t & 63;
    const int lr = l & 31, lg = l >> 5;
    const int m0 = (w >> 1) * 32, n0 = (w & 1) * 64;

    // MFMA-role edge (one per lane)
    const int lsA   = (lbase + m0 + lr < cnt) ? (lbase + m0 + lr) : (cnt - 1);
    const int slotA = slo + lsA;
    const int siA = esnd[slotA];
    const int riA = ercv[slotA];

    // epilogue-role edge (4 threads per edge)
    const int me = t >> 2, q = t & 3;
    const int lsE0 = lbase + me;
    const bool veE = lsE0 < cnt;
    const int lsE = veE ? lsE0 : (cnt - 1);
    const int slotE = slo + lsE;
    const int siE = esnd[slotE];

    // ---- layer-1 A fragments: direct global -> registers ----
    bf16x8 afr[11];
    {
        const u16* sp = ns_bf + (size_t)siA * 64 + lg * 8;
        const u16* rp = ns_bf + (size_t)riA * 64 + lg * 8;
        const u16* fp = sefp + (size_t)slotA * 32 + lg * 8;
        #pragma unroll
        for (int ks = 0; ks < 4; ++ks) afr[ks]     = *(const bf16x8*)(sp + ks * 16);
        #pragma unroll
        for (int ks = 0; ks < 4; ++ks) afr[4 + ks] = *(const bf16x8*)(rp + ks * 16);
        afr[8] = *(const bf16x8*)(fp);
        afr[9] = *(const bf16x8*)(fp + 16);
        bf16x8 z = (bf16x8)0;
        if (lg == 0) z[0] = (short)lenp[slotA];
        afr[10] = z;
    }

    const u16* w1t = wt;
    const u16* w2t = wt + 128 * W1K;
    const u16* w3t = w2t + 128 * 128;

    f32x16 acc0, acc1;

    // ---------- layer 1 (A from registers, B streamed from global/L2) ----------
    #pragma unroll
    for (int i = 0; i < 16; ++i) { acc0[i] = 0.f; acc1[i] = 0.f; }
    {
        const u16* bp0 = w1t + (size_t)(n0 + lr) * W1K + lg * 8;
        const u16* bp1 = bp0 + 32 * W1K;
        #pragma unroll
        for (int ks = 0; ks < 11; ++ks) {
            bf16x8 bv0 = *(const bf16x8*)(bp0 + ks * 16);
            bf16x8 bv1 = *(const bf16x8*)(bp1 + ks * 16);
            acc0 = __builtin_amdgcn_mfma_f32_32x32x16_bf16(afr[ks], bv0, acc0, 0, 0, 0);
            acc1 = __builtin_amdgcn_mfma_f32_32x32x16_bf16(afr[ks], bv1, acc1, 0, 0, 0);
        }
    }
    {   const float bv0 = b1[n0 + lr], bv1 = b1[n0 + 32 + lr];
        #pragma unroll
        for (int r = 0; r < 16; ++r) {
            const int row = (r & 3) + 8 * (r >> 2) + 4 * lg;
            Hb[(m0 + row) * HST + n0 + lr]      = f2bf(fsilu(acc0[r] + bv0));
            Hb[(m0 + row) * HST + n0 + 32 + lr] = f2bf(fsilu(acc1[r] + bv1));
        }
    }
    __syncthreads();

    auto run_layer_lds = [&](const u16* Wg, f32x16& a0, f32x16& a1) {
        #pragma unroll
        for (int i = 0; i < 16; ++i) { a0[i] = 0.f; a1[i] = 0.f; }
        const u16* ap  = Hb + (m0 + lr) * HST + lg * 8;
        const u16* bp0 = Wg + (size_t)(n0 + lr) * 128 + lg * 8;
        const u16* bp1 = bp0 + 32 * 128;
        #pragma unroll
        for (int ks = 0; ks < 8; ++ks) {
            bf16x8 af  = *(const bf16x8*)(ap  + ks * 16);
            bf16x8 bv0 = *(const bf16x8*)(bp0 + ks * 16);
            bf16x8 bv1 = *(const bf16x8*)(bp1 + ks * 16);
            a0 = __builtin_amdgcn_mfma_f32_32x32x16_bf16(af, bv0, a0, 0, 0, 0);
            a1 = __builtin_amdgcn_mfma_f32_32x32x16_bf16(af, bv1, a1, 0, 0, 0);
        }
    };

    // ---------- layer 2 ----------
    run_layer_lds(w2t, acc0, acc1);
    __syncthreads();
    {   const float bv0 = b2[n0 + lr], bv1 = b2[n0 + 32 + lr];
        #pragma unroll
        for (int r = 0; r < 16; ++r) {
            const int row = (r & 3) + 8 * (r >> 2) + 4 * lg;
            Hb[(m0 + row) * HST + n0 + lr]      = f2bf(fsilu(acc0[r] + bv0));
            Hb[(m0 + row) * HST + n0 + 32 + lr] = f2bf(fsilu(acc1[r] + bv1));
        }
    }
    __syncthreads();

    // ---------- layer 3 (mix) ----------
    run_layer_lds(w3t, acc0, acc1);
    __syncthreads();
    {   const float bv0 = b3[n0 + lr], bv1 = b3[n0 + 32 + lr];
        #pragma unroll
        for (int r = 0; r < 16; ++r) {
            const int row = (r & 3) + 8 * (r >> 2) + 4 * lg;
            Hb[(m0 + row) * HST + n0 + lr]      = f2bf(acc0[r] + bv0);
            Hb[(m0 + row) * HST + n0 + 32 + lr] = f2bf(acc1[r] + bv1);
        }
    }
    __syncthreads();

    // ---------- factored message epilogue: 4 threads/edge ----------
    if (veE) {
        const u16* Hr = Hb + me * HST;
        u16* mrow = msg + (size_t)lsE * MROW;
        const float evx = evp[(size_t)slotE * 3 + 0];
        const float evy = evp[(size_t)slotE * 3 + 1];
        const float evz = evp[(size_t)slotE * 3 + 2];

        // sender scalars k=16q..16q+15 and vectors c=8q..8q+7 direct from global
        u16 sa[16], va[24];
        {
            const u16* nsrow = ns_bf + (size_t)siE * 64 + 16 * q;
            *(u16x8*)(sa)     = *(const u16x8*)(nsrow);
            *(u16x8*)(sa + 8) = *(const u16x8*)(nsrow + 8);
            const u16* nvrow = nv_bf + (size_t)siE * 96 + 24 * q;
            *(u16x8*)(va)      = *(const u16x8*)(nvrow);
            *(u16x8*)(va + 8)  = *(const u16x8*)(nvrow + 8);
            *(u16x8*)(va + 16) = *(const u16x8*)(nvrow + 16);
        }

        float m0v[8], m1bv[24];
        #pragma unroll
        for (int j = 0; j < 8; ++j) {
            const int c = 8 * q + j;
            const float vx = bf2f(va[3 * j]), vy = bf2f(va[3 * j + 1]), vz = bf2f(va[3 * j + 2]);
            m0v[j] = (vx * evx + vy * evy + vz * evz) * INV_SQ3 * bf2f(Hr[c]);
            const float gb = bf2f(Hr[96 + c]) * INV_SQ2;
            m1bv[3 * j + 0] = (vy * evz - vz * evy) * gb;
            m1bv[3 * j + 1] = (vz * evx - vx * evz) * gb;
            m1bv[3 * j + 2] = (vx * evy - vy * evx) * gb;
        }
        {   uint4 o = { cvtpk(m0v[0], m0v[1]), cvtpk(m0v[2], m0v[3]),
                        cvtpk(m0v[4], m0v[5]), cvtpk(m0v[6], m0v[7]) };
            *(uint4*)(mrow + 8 * q) = o;
        }
        {   u16* dst = mrow + 96 + 24 * q;
            uint4 o0 = { cvtpk(m1bv[0],  m1bv[1]),  cvtpk(m1bv[2],  m1bv[3]),
                         cvtpk(m1bv[4],  m1bv[5]),  cvtpk(m1bv[6],  m1bv[7])  };
            uint4 o1 = { cvtpk(m1bv[8],  m1bv[9]),  cvtpk(m1bv[10], m1bv[11]),
                         cvtpk(m1bv[12], m1bv[13]), cvtpk(m1bv[14], m1bv[15]) };
            uint4 o2 = { cvtpk(m1bv[16], m1bv[17]), cvtpk(m1bv[18], m1bv[19]),
                         cvtpk(m1bv[20], m1bv[21]), cvtpk(m1bv[22], m1bv[23]) };
            *(uint4*)(dst)      = o0;
            *(uint4*)(dst + 8)  = o1;
            *(uint4*)(dst + 16) = o2;
        }
        {   float sg[16];
            #pragma unroll
            for (int j = 0; j < 16; ++j) {
                const int k = 16 * q + j;
                sg[j] = bf2f(sa[j]) * bf2f(Hr[32 + k]);
            }
            u16* dst = mrow + 32 + 16 * q;
            uint4 o0 = { cvtpk(sg[0],  sg[1]),  cvtpk(sg[2],  sg[3]),
                         cvtpk(sg[4],  sg[5]),  cvtpk(sg[6],  sg[7])  };
            uint4 o1 = { cvtpk(sg[8],  sg[9]),  cvtpk(sg[10], sg[11]),
                         cvtpk(sg[12], sg[13]), cvtpk(sg[14], sg[15]) };
            *(uint4*)(dst)     = o0;
            *(uint4*)(dst + 8) = o1;
        }
        if (q == 0) {
            uint4 e4 = { __builtin_bit_cast(unsigned, evx),
                         __builtin_bit_cast(unsigned, evy),
                         __builtin_bit_cast(unsigned, evz), 0u };
            *(uint4*)(mrow + 192) = e4;
            uint4 z4 = { 0u, 0u, 0u, 0u };
            *(uint4*)(mrow + 200) = z4;
        }
    }
}

// ==================== phase 2: paired streaming gather with rank-1 expansion ====================

__global__ __launch_bounds__(256)
void msg_gather_seq(const int* __restrict__ rowp,
                    const u16* __restrict__ msg,
                    float* __restrict__ out,
                    int slo, int shi, int first)
{
    __shared__ float oacc[4][OUTC];

    const int gw = (blockIdx.x * 256 + threadIdx.x) >> 6;   // node
    const int l  = threadIdx.x & 63;
    const bool nvalid = gw < N_NODES;

    const int rp0 = nvalid ? rowp[gw] : 0;
    const int rp1 = nvalid ? rowp[gw + 1] : 0;
    const int lo = rp0 > slo ? rp0 : slo;
    const int hi = rp1 < shi ? rp1 : shi;
    const int n  = hi > lo ? hi - lo : 0;

    const int half = (l >= 26) ? 1 : 0;
    const int sl   = l - 26 * half;
    const bool lact = (l < 52) && (sl < 24);
    const int seg  = (sl < 4) ? 0 : (sl < 12 ? 1 : 2);

    float acc[24];
    #pragma unroll
    for (int i = 0; i < 24; ++i) acc[i] = 0.f;

    const u16* mb = msg + (size_t)(lo - slo) * MROW;

    auto body = [&](int row) {
        const u16x8 v = *(const u16x8*)(mb + (size_t)row * MROW + sl * 8);
        if (seg == 1) {
            const float4 e4 = *(const float4*)(mb + (size_t)row * MROW + 192);
            #pragma unroll
            for (int i = 0; i < 8; ++i) {
                const float s = bf2f(v[i]);
                acc[3 * i + 0] += s * e4.x;
                acc[3 * i + 1] += s * e4.y;
                acc[3 * i + 2] += s * e4.z;
            }
        } else {
            #pragma unroll
            for (int i = 0; i < 8; ++i) acc[i] += bf2f(v[i]);
        }
    };

    int j = 0;
    for (; j + 4 <= n; j += 4) {
        if (lact) { body(j + half); body(j + 2 + half); }
    }
    for (; j + 2 <= n; j += 2) {
        if (lact) body(j + half);
    }
    if (j < n && half == 0 && lact) body(j);

    float* oa = oacc[(threadIdx.x >> 6)];

    if (half == 0 && lact) {
        if (seg == 0) {
            #pragma unroll
            for (int i = 0; i < 8; ++i) oa[sl * 8 + i] = acc[i];
        } else if (seg == 1) {
            const int k0 = (sl - 4) * 8;
            #pragma unroll
            for (int i = 0; i < 8; ++i) {
                oa[32 + 3 * (k0 + i) + 0] = acc[3 * i + 0];
                oa[32 + 3 * (k0 + i) + 1] = acc[3 * i + 1];
                oa[32 + 3 * (k0 + i) + 2] = acc[3 * i + 2];
            }
        } else {
            const int c0 = (sl - 12) * 8;
            #pragma unroll
            for (int i = 0; i < 8; ++i) oa[224 + c0 + i] = acc[i];
        }
    }
    __syncthreads();
    if (half == 1 && lact) {
        if (seg == 0) {
            #pragma unroll
            for (int i = 0; i < 8; ++i) oa[sl * 8 + i] += acc[i];
        } else if (seg == 1) {
            const int k0 = (sl - 4) * 8;
            #pragma unroll
            for (int i = 0; i < 8; ++i) {
                oa[32 + 3 * (k0 + i) + 0] += acc[3 * i + 0];
                oa[32 + 3 * (k0 + i) + 1] += acc[3 * i + 1];
                oa[32 + 3 * (k0 + i) + 2] += acc[3 * i + 2];
            }
        } else {
            const int c0 = (sl - 12) * 8;
            #pragma unroll
            for (int i = 0; i < 8; ++i) oa[224 + c0 + i] += acc[i];
        }
    }
    __syncthreads();

    if (nvalid && l < 40) {
        float r[8];
        #pragma unroll
        for (int i = 0; i < 8; ++i) r[i] = oa[l * 8 + i] * INV_AVG;
        float* orow = out + (size_t)gw * OUTC + l * 8;
        if (first) {
            *(float4*)(orow)     = make_float4(r[0], r[1], r[2], r[3]);
            *(float4*)(orow + 4) = make_float4(r[4], r[5], r[6], r[7]);
        } else if (n > 0) {
            float4 p0 = *(const float4*)(orow);
            float4 p1 = *(const float4*)(orow + 4);
            p0.x += r[0]; p0.y += r[1]; p0.z += r[2]; p0.w += r[3];
            p1.x += r[4]; p1.y += r[5]; p1.z += r[6]; p1.w += r[7];
            *(float4*)(orow)     = p0;
            *(float4*)(orow + 4) = p1;
        }
    }
}

// ==================== last-resort fallback: atomic fused ====================

__global__ __launch_bounds__(256, 2)
void fused_mpconv_atomic(const float* __restrict__ node_scalars,
                         const float* __restrict__ node_vectors,
                         const float* __restrict__ edge_vec,
                         const float* __restrict__ sef,
                         const float* __restrict__ lengths,
                         const int* __restrict__ senders,
                         const int* __restrict__ receivers,
                         const float* __restrict__ W1, const float* __restrict__ b1,
                         const float* __restrict__ W2, const float* __restrict__ b2,
                         const float* __restrict__ W3, const float* __restrict__ b3,
                         float* __restrict__ out)
{
    __shared__ u16 A [EB * KP1];
    __shared__ u16 VS[EB * KV];
    __shared__ u16 Hb[EB * KH];
    __shared__ u16 Wt[2][128 * WTS];
    __shared__ float evl[3][EB];
    __shared__ int sidx[EB], ridx[EB];

    const int t = threadIdx.x;
    const int ebase = blockIdx.x * EB;

    {   const int e = t & 63, sub = t >> 6;
        const int eg = ebase + e; const bool ve = eg < N_EDGES;
        if (sub == 0)      sidx[e] = ve ? senders[eg] : 0;
        else if (sub == 1) ridx[e] = ve ? receivers[eg] : 0;
        else if (sub == 2) {
            evl[0][e] = ve ? edge_vec[(size_t)eg * 3 + 0] : 0.f;
            evl[1][e] = ve ? edge_vec[(size_t)eg * 3 + 1] : 0.f;
            evl[2][e] = ve ? edge_vec[(size_t)eg * 3 + 2] : 0.f;
        }
    }
    __syncthreads();

    {   const int me = t >> 2, q = t & 3;
        const int eg = ebase + me; const bool ve = eg < N_EDGES;
        const int si = sidx[me], ri = ridx[me];
        u16* Ar = A + me * KP1;
        stage16(node_scalars + (size_t)si * 64 + q * 16, Ar + q * 16,       ve);
        stage16(node_scalars + (size_t)ri * 64 + q * 16, Ar + 64 + q * 16,  ve);
        stage8 (sef          + (size_t)eg * 32 + q * 8,  Ar + 128 + q * 8,  ve);
        u16x8 zz = (u16x8)0;
        *(u16x8*)(Ar + 160 + q * 8) = zz;
        if (q == 0) *(u16x8*)(Ar + 192) = zz;
        stage16(node_vectors + (size_t)si * 96 + q * 24,      VS + me * KV + q * 24,      ve);
        stage8 (node_vectors + (size_t)si * 96 + q * 24 + 16, VS + me * KV + q * 24 + 16, ve);
        if (q == 0) Ar[160] = f2bf(ve ? lengths[eg] : 0.f);
    }
    __syncthreads();

    const int w  = t >> 6, l = t & 63;
    const int lr = l & 31;
    const int lg = l >> 5;
    const int m0 = (w >> 1) * 32;
    const int n0 = (w & 1) * 64;

    f32x16 acc0, acc1;
    const int n  = t & 127, ph = t >> 7;

    auto run_layer = [&](const u16* Asrc, int astr, const float* Wg, int Kr, int nsteps,
                         f32x16& a0, f32x16& a1) {
        #pragma unroll
        for (int i = 0; i < 16; ++i) { a0[i] = 0.f; a1[i] = 0.f; }
        #pragma unroll
        for (int i = 0; i < 4; ++i) {
            int kl = (i * 2 + ph) * 2;
            float v0 = (kl     < Kr) ? Wg[(size_t)kl * 128 + n]       : 0.f;
            float v1 = (kl + 1 < Kr) ? Wg[(size_t)(kl + 1) * 128 + n] : 0.f;
            *(unsigned*)&Wt[0][n * WTS + kl] = cvtpk(v0, v1);
        }
        __syncthreads();
        const u16* ap = Asrc + (m0 + lr) * astr + lg * 8;
        for (int ks = 0; ks < nsteps; ++ks) {
            const int cur = ks & 1;
            float v0[4], v1[4];
            const int kb = (ks + 1) * 16;
            if (ks + 1 < nsteps) {
                #pragma unroll
                for (int i = 0; i < 4; ++i) {
                    int kg = kb + (i * 2 + ph) * 2;
                    v0[i] = (kg     < Kr) ? Wg[(size_t)kg * 128 + n]       : 0.f;
                    v1[i] = (kg + 1 < Kr) ? Wg[(size_t)(kg + 1) * 128 + n] : 0.f;
                }
            }
            bf16x8 af = *(const bf16x8*)(ap + ks * 16);
            bf16x8 bf0 = *(const bf16x8*)(&Wt[cur][(n0      + lr) * WTS + lg * 8]);
            bf16x8 bf1 = *(const bf16x8*)(&Wt[cur][(n0 + 32 + lr) * WTS + lg * 8]);
            a0 = __builtin_amdgcn_mfma_f32_32x32x16_bf16(af, bf0, a0, 0, 0, 0);
            a1 = __builtin_amdgcn_mfma_f32_32x32x16_bf16(af, bf1, a1, 0, 0, 0);
            if (ks + 1 < nsteps) {
                #pragma unroll
                for (int i = 0; i < 4; ++i) {
                    int kl = (i * 2 + ph) * 2;
                    *(unsigned*)&Wt[cur ^ 1][n * WTS + kl] = cvtpk(v0[i], v1[i]);
                }
            }
            __syncthreads();
        }
    };

    run_layer(A, KP1, W1, 161, 11, acc0, acc1);
    {   const float bv0 = b1[n0 + lr], bv1 = b1[n0 + 32 + lr];
        #pragma unroll
        for (int r = 0; r < 16; ++r) {
            const int row = (r & 3) + 8 * (r >> 2) + 4 * lg;
            Hb[(m0 + row) * KH + n0 + lr]      = f2bf(fsilu(acc0[r] + bv0));
            Hb[(m0 + row) * KH + n0 + 32 + lr] = f2bf(fsilu(acc1[r] + bv1));
        }
    }
    __syncthreads();

    run_layer(Hb, KH, W2, 128, 8, acc0, acc1);
    __syncthreads();
    {   const float bv0 = b2[n0 + lr], bv1 = b2[n0 + 32 + lr];
        #pragma unroll
        for (int r = 0; r < 16; ++r) {
            const int row = (r & 3) + 8 * (r >> 2) + 4 * lg;
            Hb[(m0 + row) * KH + n0 + lr]      = f2bf(fsilu(acc0[r] + bv0));
            Hb[(m0 + row) * KH + n0 + 32 + lr] = f2bf(fsilu(acc1[r] + bv1));
        }
    }
    __syncthreads();

    run_layer(Hb, KH, W3, 128, 8, acc0, acc1);
    __syncthreads();
    {   const float bv0 = b3[n0 + lr], bv1 = b3[n0 + 32 + lr];
        #pragma unroll
        for (int r = 0; r < 16; ++r) {
            const int row = (r & 3) + 8 * (r >> 2) + 4 * lg;
            Hb[(m0 + row) * KH + n0 + lr]      = f2bf(acc0[r] + bv0);
            Hb[(m0 + row) * KH + n0 + 32 + lr] = f2bf(acc1[r] + bv1);
        }
    }
    __syncthreads();

    {   const int me = t >> 2, r = t & 3;
        const int eg2 = ebase + me;
        if (eg2 < N_EDGES) {
            const int row = ridx[me];
            const float evx = evl[0][me], evy = evl[1][me], evz = evl[2][me];
            float* orow = out + (size_t)row * OUTC;
            const u16* Ar = A  + me * KP1;
            const u16* Vr = VS + me * KV;
            const u16* Hr = Hb + me * KH;
            for (int col = r; col < OUTC; col += 4) {
                float val;
                if (col < 32) {
                    const int c = col;
                    const float vx = bf2f(Vr[3 * c]), vy = bf2f(Vr[3 * c + 1]), vz = bf2f(Vr[3 * c + 2]);
                    val = (vx * evx + vy * evy + vz * evz) * INV_SQ3 * bf2f(Hr[c]);
                } else {
                    const int idx = col - 32;
                    const int k = idx / 3;
                    const int d = idx - 3 * k;
                    const float g = bf2f(Hr[32 + k]);
                    if (k < 64) {
                        const float evd = (d == 0) ? evx : ((d == 1) ? evy : evz);
                        val = bf2f(Ar[k]) * evd * g;
                    } else {
                        const int c = k - 64;
                        const float vx = bf2f(Vr[3 * c]), vy = bf2f(Vr[3 * c + 1]), vz = bf2f(Vr[3 * c + 2]);
                        float cr;
                        if (d == 0)      cr = vy * evz - vz * evy;
                        else if (d == 1) cr = vz * evx - vx * evz;
                        else             cr = vx * evy - vy * evx;
                        val = cr * INV_SQ2 * g;
                    }
                }
                atomicAdd(&orow[col], val * INV_AVG);
            }
        }
    }
}

// ==================== launch ====================

extern "C" void kernel_launch(void* const* d_in, const int* in_sizes, int n_in,
                              void* d_out, int out_size, void* d_ws, size_t ws_size,
                              hipStream_t stream) {
    (void)in_sizes; (void)n_in;
    const float* node_scalars = (const float*)d_in[0];
    const float* node_vectors = (const float*)d_in[1];
    const float* edge_vec     = (const float*)d_in[2];
    const float* sef          = (const float*)d_in[3];
    const float* lengths      = (const float*)d_in[4];
    const int*   senders      = (const int*)d_in[5];
    const int*   receivers    = (const int*)d_in[6];
    const float* W1 = (const float*)d_in[7];
    const float* b1 = (const float*)d_in[8];
    const float* W2 = (const float*)d_in[9];
    const float* b2 = (const float*)d_in[10];
    const float* W3 = (const float*)d_in[11];
    const float* b3 = (const float*)d_in[12];
    float* out = (float*)d_out;

    auto align256 = [](size_t x) { return (x + 255) & ~(size_t)255; };

    size_t off = 0;
    const size_t o_counts  = off; off += align256((size_t)N_NODES * sizeof(int));
    const size_t o_rowp    = off; off += align256((size_t)(N_NODES + 1) * sizeof(int));
    const size_t o_cursors = off; off += align256((size_t)(N_NODES + 1) * sizeof(int));
    const size_t o_part    = off; off += align256(64 * sizeof(int));
    const size_t o_esnd    = off; off += align256((size_t)N_EDGES * sizeof(int));
    const size_t o_ercv    = off; off += align256((size_t)N_EDGES * sizeof(int));
    const size_t o_wt      = off; off += align256((size_t)WT_TOTAL * sizeof(u16));
    const size_t o_nsb     = off; off += align256((size_t)NS_ELEMS * sizeof(u16));
    const size_t o_nvb     = off; off += align256((size_t)NV_ELEMS * sizeof(u16));
    const size_t o_sefp    = off; off += align256((size_t)N_EDGES * 32 * sizeof(u16));
    const size_t o_lenp    = off; off += align256((size_t)N_EDGES * sizeof(u16));
    const size_t o_evp     = off; off += align256((size_t)N_EDGES * 3 * sizeof(float));
    const size_t o_msg     = off;
    const size_t fixed_bytes = off;

    const size_t ROWB = (size_t)MROW * sizeof(u16);   // 416
    long Ec = 0;
    if (ws_size > fixed_bytes + (size_t)128 * ROWB) {
        size_t cap_rows = (ws_size - fixed_bytes) / ROWB;
        Ec = ((long)cap_rows - 64) / 64 * 64;
        if (Ec > N_EDGES) Ec = N_EDGES;
    }

    char* ws = (char*)d_ws;

    if (Ec >= 64) {
        int* counts  = (int*)(ws + o_counts);
        int* rowp    = (int*)(ws + o_rowp);
        int* cursors = (int*)(ws + o_cursors);
        int* part    = (int*)(ws + o_part);
        int* esnd    = (int*)(ws + o_esnd);
        int* ercv    = (int*)(ws + o_ercv);
        u16* wt      = (u16*)(ws + o_wt);
        u16* nsb     = (u16*)(ws + o_nsb);
        u16* nvb     = (u16*)(ws + o_nvb);
        u16* sefp    = (u16*)(ws + o_sefp);
        u16* lenp    = (u16*)(ws + o_lenp);
        float* evp   = (float*)(ws + o_evp);
        u16* msg     = (u16*)(ws + o_msg);

        hipMemsetAsync(counts, 0, (size_t)N_NODES * sizeof(int), stream);
        hist_kernel<<<(N_EDGES + 255) / 256, 256, 0, stream>>>(receivers, counts);
        scan_k1<<<NBLK1, 256, 0, stream>>>(counts, rowp, part);
        scan_k2<<<1, 64, 0, stream>>>(part);
        scan_k3<<<NBLK1, 256, 0, stream>>>(rowp, part, cursors);
        fill_kernel<<<(N_EDGES + 255) / 256, 256, 0, stream>>>(
            receivers, senders, sef, edge_vec, lengths,
            cursors, esnd, ercv, sefp, lenp, evp);
        wcvt_kernel<<<(WT_TOTAL + 255) / 256, 256, 0, stream>>>(W1, W2, W3, wt);
        {
            const int tot2 = (NS_ELEMS + NV_ELEMS) / 2;
            nodecvt_kernel<<<(tot2 + 255) / 256, 256, 0, stream>>>(
                node_scalars, node_vectors, nsb, nvb);
        }

        const int nchunks = (int)((N_EDGES + Ec - 1) / Ec);
        const int ggrid = (N_NODES * 64 + 255) / 256;
        for (int c = 0; c < nchunks; ++c) {
            const int slo = (int)(c * Ec);
            const int cnt = (int)((N_EDGES - slo < Ec) ? (N_EDGES - slo) : Ec);
            mlp_msg_kernel<<<(cnt + EB - 1) / EB, 256, 0, stream>>>(
                nsb, nvb, sefp, lenp, evp, esnd, ercv,
                wt, b1, b2, b3, msg, slo, cnt);
            msg_gather_seq<<<ggrid, 256, 0, stream>>>(
                rowp, msg, out, slo, slo + cnt, c == 0 ? 1 : 0);
        }
    } else {
        hipMemsetAsync(out, 0, (size_t)out_size * sizeof(float), stream);
        fused_mpconv_atomic<<<(N_EDGES + EB - 1) / EB, 256, 0, stream>>>(
            node_scalars, node_vectors, edge_vec, sef, lengths,
            senders, receivers, W1, b1, W2, b2, W3, b3, out);
    }
}